// Round 4
// baseline (136.128 us; speedup 1.0000x reference)
//
#include <hip/hip_runtime.h>
#include <math.h>

constexpr int NFFT = 256;
constexpr int HOP  = 216;
constexpr int PAD  = 20;

// LDS geometry (floats)
constexpr int TRS = 20;    // transpose row stride (16B-aligned rows: 20*4=80B)
constexpr int TPS = 328;   // transpose plane stride per fm (328%32==8 -> 2-way col reads)
constexpr int TSZ = 8 * TPS;          // 2624: transpose/C region (C needs 4*512=2048 <= 2624)
constexpr int IPS = 312;   // IPAD row stride per frame (312%4==0, %32==24)
constexpr int IP0 = TSZ;              // IPAD base
constexpr int SMF = TSZ + 4 * IPS;    // 2624+1248 = 3872 floats = 15488 B

__device__ __forceinline__ void cmul(float& dr, float& di, float ar, float ai, float br, float bi) {
    dr = ar * br - ai * bi;
    di = ar * bi + ai * br;
}

constexpr float TC16[10] = {1.f, 0.92387953f, 0.70710678f, 0.38268343f, 0.f,
                            -0.38268343f, -0.70710678f, -0.92387953f, -1.f, -0.92387953f};
constexpr float TS16[10] = {0.f, 0.38268343f, 0.70710678f, 0.92387953f, 1.f,
                            0.92387953f, 0.70710678f, 0.38268343f, 0.f, -0.38268343f};

// In-register 16-point DFT, natural order in/out (verified in round 3).
template<int SGN>
__device__ __forceinline__ void fft16(float xr[16], float xi[16]) {
    constexpr float S = (float)SGN;
    float tr[4][4], ti[4][4];
    #pragma unroll
    for (int n1 = 0; n1 < 4; ++n1) {
        float ar = xr[n1],      ai = xi[n1];
        float br = xr[n1 + 4],  bi = xi[n1 + 4];
        float cr = xr[n1 + 8],  ci = xi[n1 + 8];
        float dr = xr[n1 + 12], di = xi[n1 + 12];
        float Ar = ar + cr, Ai = ai + ci, Br = ar - cr, Bi = ai - ci;
        float Cr = br + dr, Ci = bi + di, Dr = br - dr, Di = bi - di;
        tr[n1][0] = Ar + Cr;      ti[n1][0] = Ai + Ci;
        tr[n1][2] = Ar - Cr;      ti[n1][2] = Ai - Ci;
        tr[n1][1] = Br - S * Di;  ti[n1][1] = Bi + S * Dr;
        tr[n1][3] = Br + S * Di;  ti[n1][3] = Bi - S * Dr;
    }
    #pragma unroll
    for (int n1 = 1; n1 < 4; ++n1) {
        #pragma unroll
        for (int k2 = 1; k2 < 4; ++k2) {
            const int m = n1 * k2;
            const float wr = TC16[m], wi = S * TS16[m];
            float vr, vi;
            cmul(vr, vi, tr[n1][k2], ti[n1][k2], wr, wi);
            tr[n1][k2] = vr; ti[n1][k2] = vi;
        }
    }
    #pragma unroll
    for (int k2 = 0; k2 < 4; ++k2) {
        float ar = tr[0][k2], ai = ti[0][k2];
        float br = tr[1][k2], bi = ti[1][k2];
        float cr = tr[2][k2], ci = ti[2][k2];
        float dr = tr[3][k2], di = ti[3][k2];
        float Ar = ar + cr, Ai = ai + ci, Br = ar - cr, Bi = ai - ci;
        float Cr = br + dr, Ci = bi + di, Dr = br - dr, Di = bi - di;
        xr[k2]      = Ar + Cr;     xi[k2]      = Ai + Ci;
        xr[k2 + 8]  = Ar - Cr;     xi[k2 + 8]  = Ai - Ci;
        xr[k2 + 4]  = Br - S * Di; xi[k2 + 4]  = Bi + S * Dr;
        xr[k2 + 12] = Br + S * Di; xi[k2 + 12] = Bi - S * Dr;
    }
}

// Zero only the double-covered overlap stripes: out index (b*Lout + s*HOP - PAD)*4 + r,
// r < 160, s in [1, steps). Vectorized float4.
__global__ __launch_bounds__(256)
void zero_overlap(float4* __restrict__ out4, int B, int steps, int Lout) {
    const int total = B * (steps - 1) * 40;
    for (int idx = blockIdx.x * 256 + threadIdx.x; idx < total; idx += gridDim.x * 256) {
        const int j  = idx / 40;          // stripe id
        const int r4 = idx - j * 40;
        const int b  = j / (steps - 1);
        const int s  = j - b * (steps - 1) + 1;
        out4[(size_t)b * Lout + (size_t)s * HOP - PAD + r4] = make_float4(0.f, 0.f, 0.f, 0.f);
    }
}

// Block = 128 threads = 4 frames x 2 modes x 16 lanes.
__global__ __launch_bounds__(128)
void eq_pbc_kernel(const float* __restrict__ x_real,
                   const float* __restrict__ x_imag,
                   const float* __restrict__ task_info,
                   const float* __restrict__ h_real,
                   const float* __restrict__ h_imag,
                   float* __restrict__ out,
                   int B, int L, int steps)
{
    __shared__ __align__(16) float SM[SMF];

    const int tid = threadIdx.x;
    const int i   = tid & 15;
    const int fm  = tid >> 4;     // 0..7
    const int fr  = tid >> 5;     // 0..3
    const int md  = (tid >> 4) & 1;
    const int u   = tid & 31;

    const int G = B * steps;
    int g = blockIdx.x * 4 + fr;
    const bool valid = (g < G);
    if (!valid) g = G - 1;
    const int b  = g / steps;
    const int s  = g - b * steps;
    const int l0 = s * HOP;

    // zero IPAD (atomic-add target); completes before first use (B1..B3 precede atomics)
    #pragma unroll
    for (int j = tid; j < 4 * IPS / 4; j += 128)
        *(float4*)&SM[IP0 + 4 * j] = make_float4(0.f, 0.f, 0.f, 0.f);

    float sb, cb;
    __sincosf(-6.2831853071795864f * (1.0f / 256.0f) * (float)i, &sb, &cb);

    // ---- load: thread holds x[l0 + i + 16*n2], its own mode ----
    float xr[16], xi[16];
    {
        const size_t base = ((size_t)b * L + l0) * 2 + (size_t)(2 * i + md);
        #pragma unroll
        for (int n2 = 0; n2 < 16; ++n2) {
            xr[n2] = x_real[base + 32 * n2];
            xi[n2] = x_imag[base + 32 * n2];
        }
    }

    // ---- forward step A + twiddle W256^{i*k2} ----
    fft16<-1>(xr, xi);
    {
        float wr[16], wi[16];
        wr[1] = cb; wi[1] = sb;
        #pragma unroll
        for (int k = 2; k < 16; ++k) {
            const int h = k >> 1;
            cmul(wr[k], wi[k], wr[h], wi[h], wr[k - h], wi[k - h]);
        }
        #pragma unroll
        for (int k = 1; k < 16; ++k) {
            float vr, vi;
            cmul(vr, vi, xr[k], xi[k], wr[k], wi[k]);
            xr[k] = vr; xi[k] = vi;
        }
    }

    // ---- forward transpose, single plane, re then im ----
    const int tb = fm * TPS;
    #pragma unroll
    for (int c = 0; c < 4; ++c)
        *(float4*)&SM[tb + i * TRS + 4 * c] = make_float4(xr[4*c], xr[4*c+1], xr[4*c+2], xr[4*c+3]);
    __syncthreads();                      // B1
    #pragma unroll
    for (int n1 = 0; n1 < 16; ++n1) xr[n1] = SM[tb + n1 * TRS + i];
    __syncthreads();                      // B2
    #pragma unroll
    for (int c = 0; c < 4; ++c)
        *(float4*)&SM[tb + i * TRS + 4 * c] = make_float4(xi[4*c], xi[4*c+1], xi[4*c+2], xi[4*c+3]);
    __syncthreads();                      // B3
    #pragma unroll
    for (int n1 = 0; n1 < 16; ++n1) xi[n1] = SM[tb + n1 * TRS + i];

    // ---- forward step B: X[f = i + 16*k1] in reg k1 ----
    fft16<-1>(xr, xi);

    // ---- intensity: atomic-add both modes into padded IPAD ----
    {
        float* ip = &SM[IP0 + fr * IPS];
        #pragma unroll
        for (int k1 = 0; k1 < 16; ++k1) {
            const int f = i + 16 * k1;
            const float v = xr[k1] * xr[k1] + xi[k1] * xi[k1];
            atomicAdd(&ip[f + PAD], v);
            if (f < PAD)         atomicAdd(&ip[f + 276], v);   // right pad
            if (f >= NFFT - PAD) atomicAdd(&ip[f - 236], v);   // left pad
        }
    }
    __syncthreads();                      // B4

    // ---- FIR: thread u of frame fr -> outputs f0=8u..8u+7; c into T region ----
    {
        float W[48];
        #pragma unroll
        for (int c = 0; c < 12; ++c)
            *(float4*)&W[4 * c] = *(const float4*)&SM[IP0 + fr * IPS + u * 8 + 4 * c];
        float phr[8], phi8[8];
        #pragma unroll
        for (int o = 0; o < 8; ++o) { phr[o] = 0.f; phi8[o] = 0.f; }
        #pragma unroll
        for (int t = 0; t < 41; ++t) {
            const float htr = h_real[t], hti = h_imag[t];
            #pragma unroll
            for (int o = 0; o < 8; ++o) {
                phr[o]  = fmaf(W[o + t], htr, phr[o]);
                phi8[o] = fmaf(W[o + t], hti, phi8[o]);
            }
        }
        const float P = exp2f(task_info[4 * b] * 0.33219280948873623f) * 0.5f;
        float4 v0, v1;
        v0.x = 1.f - P * phi8[0]; v0.y = 1.f - P * phi8[1]; v0.z = 1.f - P * phi8[2]; v0.w = 1.f - P * phi8[3];
        v1.x = 1.f - P * phi8[4]; v1.y = 1.f - P * phi8[5]; v1.z = 1.f - P * phi8[6]; v1.w = 1.f - P * phi8[7];
        *(float4*)&SM[fr * 512 + u * 8]     = v0;
        *(float4*)&SM[fr * 512 + u * 8 + 4] = v1;
        v0.x = P * phr[0]; v0.y = P * phr[1]; v0.z = P * phr[2]; v0.w = P * phr[3];
        v1.x = P * phr[4]; v1.y = P * phr[5]; v1.z = P * phr[6]; v1.w = P * phr[7];
        *(float4*)&SM[fr * 512 + 256 + u * 8]     = v0;
        *(float4*)&SM[fr * 512 + 256 + u * 8 + 4] = v1;
    }
    __syncthreads();                      // B5

    // ---- modulate X[f] *= c[f] ----
    #pragma unroll
    for (int k1 = 0; k1 < 16; ++k1) {
        const float cr_ = SM[fr * 512 + i + 16 * k1];
        const float ci_ = SM[fr * 512 + 256 + i + 16 * k1];
        const float vr = xr[k1] * cr_ - xi[k1] * ci_;
        const float vi = xr[k1] * ci_ + xi[k1] * cr_;
        xr[k1] = vr; xi[k1] = vi;
    }

    // ---- inverse step A + conj twiddle ----
    fft16<1>(xr, xi);
    {
        float wr[16], wi[16];
        wr[1] = cb; wi[1] = -sb;
        #pragma unroll
        for (int k = 2; k < 16; ++k) {
            const int h = k >> 1;
            cmul(wr[k], wi[k], wr[h], wi[h], wr[k - h], wi[k - h]);
        }
        #pragma unroll
        for (int k = 1; k < 16; ++k) {
            float vr, vi;
            cmul(vr, vi, xr[k], xi[k], wr[k], wi[k]);
            xr[k] = vr; xi[k] = vi;
        }
    }
    __syncthreads();                      // B6 (all C reads done; T region reused)

    // ---- inverse transpose, single plane, re then im ----
    #pragma unroll
    for (int c = 0; c < 4; ++c)
        *(float4*)&SM[tb + i * TRS + 4 * c] = make_float4(xr[4*c], xr[4*c+1], xr[4*c+2], xr[4*c+3]);
    __syncthreads();                      // B7
    #pragma unroll
    for (int k2 = 0; k2 < 16; ++k2) xr[k2] = SM[tb + k2 * TRS + i];
    __syncthreads();                      // B8
    #pragma unroll
    for (int c = 0; c < 4; ++c)
        *(float4*)&SM[tb + i * TRS + 4 * c] = make_float4(xi[4*c], xi[4*c+1], xi[4*c+2], xi[4*c+3]);
    __syncthreads();                      // B9
    #pragma unroll
    for (int k2 = 0; k2 < 16; ++k2) xi[k2] = SM[tb + k2 * TRS + i];

    // ---- inverse step B: y[i + 16*n2] (x256) ----
    fft16<1>(xr, xi);

    // ---- OLA + wsum + crop ----
    if (valid) {
        const int Lout = L - 2 * PAD;
        float* obase = out + (size_t)b * Lout * 4 + md * 2;
        #pragma unroll
        for (int n2 = 0; n2 < 16; ++n2) {
            const int n  = i + 16 * n2;
            const int la = l0 + n;
            if (la < PAD || la >= L - PAD) continue;
            const bool ov = (n < NFFT - HOP && s > 0) || (n >= HOP && s + 1 < steps);
            const float sc = (ov ? 0.5f : 1.0f) * (1.0f / 256.0f);
            float* p = obase + (size_t)(la - PAD) * 4;
            const float vr = xr[n2] * sc, vi = xi[n2] * sc;
            if (ov) { atomicAdd(p, vr); atomicAdd(p + 1, vi); }
            else    { *(float2*)p = make_float2(vr, vi); }
        }
    }
}

extern "C" void kernel_launch(void* const* d_in, const int* in_sizes, int n_in,
                              void* d_out, int out_size, void* d_ws, size_t ws_size,
                              hipStream_t stream) {
    const float* x_real    = (const float*)d_in[0];
    const float* x_imag    = (const float*)d_in[1];
    const float* task_info = (const float*)d_in[2];
    const float* h_real    = (const float*)d_in[3];
    const float* h_imag    = (const float*)d_in[4];

    const int B     = in_sizes[2] / 4;
    const int L     = in_sizes[0] / (B * 2);
    const int steps = (L - NFFT) / HOP + 1;
    const int G     = B * steps;
    const int Lout  = L - 2 * PAD;

    if (steps > 1) {
        const int total4 = B * (steps - 1) * 40;
        const int zb = (total4 + 255) / 256;
        zero_overlap<<<zb, 256, 0, stream>>>((float4*)d_out, B, steps, Lout);
    }

    eq_pbc_kernel<<<(G + 3) / 4, 128, 0, stream>>>(
        x_real, x_imag, task_info, h_real, h_imag, (float*)d_out, B, L, steps);
}